// Round 5
// baseline (941.414 us; speedup 1.0000x reference)
//
#include <hip/hip_runtime.h>

#define BB 512
#define TT 1024
#define DX 32
#define DZ 64
#define DY 256
#define ALPHA 0.125f
#define PS 68   // part_s wave-row stride: 64 + 4 pad -> bank (4w+l)%32, 2-way max

// quad_perm xor1 DPP add (folds to v_add_f32_dpp): x + x[lane^1]
__device__ __forceinline__ float dpp_add_xor1(float x) {
    int p = __builtin_amdgcn_update_dpp(0, __float_as_int(x), 0xB1, 0xF, 0xF, true);
    return x + __int_as_float(p);
}

// One batch per block, 512 threads (8 waves), 512 blocks -> 2 blocks/CU.
// R5 restructure: ONE barrier per step (was 2 + 2 cross-wave LDS turnarounds).
//  - wave w owns hid rows [32w,32w+32): m1 lane pair (2r,2r+1) computes row
//    32w+r split over z-halves, xor1-DPP completes the 64-dot. hid goes through
//    WAVE-PRIVATE hid_s[w] (lgkmcnt-ordered, no barrier).
//  - m2: lane l computes partial[z=l] over the wave's own y-slice [32w,+32)
//    from hid_s[w] (broadcast reads). No cross-lane reduce at all.
//  - the ONLY cross-wave exchange: part_s[buf][w][l] write -> __syncthreads ->
//    every wave redundantly sums the 8 partials and updates z (lane l = z l).
//    zf re-broadcast via wave-private zf_s[w] (no barrier).
//  - part_s double-buffered: WAR across steps guarded by the single barrier.
__global__ __launch_bounds__(512)
__attribute__((amdgpu_waves_per_eu(4, 4)))
void plrnn_scan(const float* __restrict__ X, const float* __restrict__ A,
                const float* __restrict__ W1, const float* __restrict__ W2,
                const float* __restrict__ h1, const float* __restrict__ h2,
                float* __restrict__ out) {
    const int b   = blockIdx.x;
    const int tid = threadIdx.x;
    const int l   = tid & 63;        // lane
    const int w   = tid >> 6;        // wave 0..7
    const int r   = l >> 1;          // m1 row-within-wave 0..31
    const int h   = l & 1;           // m1 z-half
    const int y   = 32 * w + r;      // m1 hid row

    __shared__ float zf_s[8][DZ];        // per-wave private zf copy
    __shared__ float hid_s[8][32];       // per-wave private hid slice
    __shared__ float part_s[2][8 * PS];  // cross-wave partials, double-buffered

    // ---- one-time: weight tiles into registers (64 floats/lane) ----
    float4 w2r[8];   // W2[y][32h + 4j ..+3]   (W2 is DY x DZ row-major)
    float4 w1r[8];   // W1[l][32w + 4j ..+3]   (W1 is DZ x DY row-major)
#pragma unroll
    for (int j = 0; j < 8; ++j) {
        w2r[j] = *(const float4*)&W2[y * DZ + 32 * h + 4 * j];
        w1r[j] = *(const float4*)&W1[l * DY + 32 * w + 4 * j];
    }
    const float h2i = (h == 0) ? h2[y] : 0.0f;  // bias folded into even-lane acc
    const float Al  = A[l];
    const float h1l = h1[l];

    const float* Xb = X   + (size_t)b * TT * DX;
    float*       Ob = out + (size_t)b * TT * DX;

    // ---- zf_0 = x0 (non-NaN) on first DX dims, else 0; lane l holds zf[l] ----
    float zfreg = 0.0f;
    if (l < DX) { float x0 = Xb[l]; zfreg = (x0 == x0) ? x0 : 0.0f; }
    zf_s[w][l] = zfreg;   // wave-private write; lgkmcnt orders the next read

    const float* xq = Xb + l + DX;   // X[t+1][l] stream (lanes l<DX)
    float*       oq = Ob + l;        // out[t][l] stream (wave 0, l<DX)
    const float  NANF = __int_as_float(0x7fc00000);

    auto step = [&](float* pbuf, const float xn, const int tOff) {
        // ---- m1: hid[y] = relu(W2[y]·zf + h2[y]), wave-local rows ----
        const float4* zp = (const float4*)&zf_s[w][32 * h];
        float a0 = h2i, a1 = 0.f, a2 = 0.f, a3 = 0.f;
#pragma unroll
        for (int j = 0; j < 8; ++j) {
            float4 v = zp[j];
            a0 = fmaf(w2r[j].x, v.x, a0);
            a1 = fmaf(w2r[j].y, v.y, a1);
            a2 = fmaf(w2r[j].z, v.z, a2);
            a3 = fmaf(w2r[j].w, v.w, a3);
        }
        float d1 = (a0 + a1) + (a2 + a3);
        d1 = dpp_add_xor1(d1);                 // join the two z-halves
        if (h == 0) hid_s[w][r] = fmaxf(d1, 0.0f);
        // wave-private: compiler's lgkmcnt orders write->read, no barrier

        // ---- m2: partial[z=l] over own y-slice [32w,32w+32) ----
        const float4* hp = (const float4*)&hid_s[w][0];   // broadcast reads
        float p0 = 0.f, p1 = 0.f, p2 = 0.f, p3 = 0.f;
#pragma unroll
        for (int j = 0; j < 8; ++j) {
            float4 v = hp[j];
            p0 = fmaf(w1r[j].x, v.x, p0);
            p1 = fmaf(w1r[j].y, v.y, p1);
            p2 = fmaf(w1r[j].z, v.z, p2);
            p3 = fmaf(w1r[j].w, v.w, p3);
        }
        pbuf[w * PS + l] = (p0 + p1) + (p2 + p3);

        __syncthreads();   // the ONLY barrier: all 8 partial rows visible

        // ---- redundant update on every wave: z_new[l] ----
        const float* ps = pbuf + l;
        float s = ((ps[0 * PS] + ps[1 * PS]) + (ps[2 * PS] + ps[3 * PS])) +
                  ((ps[4 * PS] + ps[5 * PS]) + (ps[6 * PS] + ps[7 * PS]));
        float zn = fmaf(Al, zfreg, s + h1l);
        if (w == 0 && l < DX) oq[tOff] = zn;
        // xn is NaN for l>=DX and for the last step -> blend skipped
        zfreg = (xn == xn) ? fmaf(ALPHA, xn, (1.0f - ALPHA) * zn) : zn;
        zf_s[w][l] = zfreg;    // wave-private re-broadcast for next m1
    };

    // unroll by 2: static part_s buffer selection
    for (int t = 0; t < TT; t += 2) {
        float xn0 = NANF, xn1 = NANF;
        if (l < DX) {
            xn0 = xq[0];                       // X[t+1][l]
            if (t + 2 < TT) xn1 = xq[DX];      // X[t+2][l]
        }
        xq += 2 * DX;
        step(&part_s[0][0], xn0, t * DX);
        step(&part_s[1][0], xn1, (t + 1) * DX);
    }
}

extern "C" void kernel_launch(void* const* d_in, const int* in_sizes, int n_in,
                              void* d_out, int out_size, void* d_ws, size_t ws_size,
                              hipStream_t stream) {
    const float* X  = (const float*)d_in[0];
    const float* A  = (const float*)d_in[1];
    const float* W1 = (const float*)d_in[2];
    const float* W2 = (const float*)d_in[3];
    const float* h1 = (const float*)d_in[4];
    const float* h2 = (const float*)d_in[5];
    float* out = (float*)d_out;

    plrnn_scan<<<BB, 512, 0, stream>>>(X, A, W1, W2, h1, h2, out);
}

// Round 6
// 799.246 us; speedup vs baseline: 1.1779x; 1.1779x over previous
//
#include <hip/hip_runtime.h>

#define BB 512
#define TT 1024
#define DX 32
#define DZ 64
#define DY 256
#define ALPHA 0.125f
#define HP 36  // hid chunk stride: 32 floats + 4 pad (8 distinct bank-quads)

typedef float v2f __attribute__((ext_vector_type(2)));

// Packed dual-FP32 FMA: d.lo = a.lo*b.lo + c.lo ; d.hi = a.hi*b.hi + c.hi.
// Full-rate on gfx950 (the 157.3 TF fp32 spec number IS the packed rate);
// plain v_fma_f32 runs at half that. Inline asm to guarantee emission.
__device__ __forceinline__ v2f pk_fma(v2f a, v2f b, v2f c) {
    asm("v_pk_fma_f32 %0, %1, %2, %0" : "+v"(c) : "v"(a), "v"(b));
    return c;
}

// DPP add: x + dpp_permuted(x), VALU pipe only.
// 0xB1 quad_perm xor1 | 0x4E quad_perm xor2 | 0x141 row_half_mirror.
template<int CTRL>
__device__ __forceinline__ float dpp_add(float x) {
    int p = __builtin_amdgcn_update_dpp(0, __float_as_int(x), CTRL, 0xF, 0xF, true);
    return x + __int_as_float(p);
}

// EXACT R1 structure (820 us: 512 thr / 8 waves, 512 blocks -> 2 blocks/CU,
// 2 LDS turnarounds + 2 barriers per step) with the two 32-FMA inner loops
// rewritten as 16 v_pk_fma_f32 each. R0-R5 established: time tracks
// (turnaround count, issue); LDS BW and barrier count are not binding.
// This round halves the FLOP-issue term and changes nothing else.
// m1: thread (y=tid>>1, h=tid&1): hidden row y over z-chunk 32h..+31;
//     xor1 DPP completes the 64-dot.
// m2: thread (z=tid>>3, oct=tid&7): latent row z over y-chunk 32*oct..+31;
//     xor1+xor2+half_mirror completes the 256-dot; update replicated
//     across the 8 oct lanes (oct==0 stores).
__global__ __launch_bounds__(512, 4)
void plrnn_scan(const float* __restrict__ X, const float* __restrict__ A,
                const float* __restrict__ W1, const float* __restrict__ W2,
                const float* __restrict__ h1, const float* __restrict__ h2,
                float* __restrict__ out) {
    const int b   = blockIdx.x;
    const int tid = threadIdx.x;

    const int y   = tid >> 1;      // m1 output row 0..255
    const int h   = tid & 1;       // m1 z-chunk
    const int z   = tid >> 3;      // m2 output row 0..63
    const int oct = tid & 7;       // m2 y-chunk
    const int wv  = tid >> 6;      // wave id 0..7

    __shared__ float zf_s[DZ];
    __shared__ float hid_s[8 * HP];

    // ---- one-time: weight tiles into v2f pairs (32 + 32 floats) ----
    v2f w2p[16];   // pairs of W2[y][32h + ...]
    v2f w1p[16];   // pairs of W1[z][32*oct + ...]
#pragma unroll
    for (int j = 0; j < 8; ++j) {
        float4 t2 = *(const float4*)&W2[y * DZ + 32 * h + 4 * j];
        float4 t1 = *(const float4*)&W1[z * DY + 32 * oct + 4 * j];
        w2p[2 * j]     = v2f{t2.x, t2.y};
        w2p[2 * j + 1] = v2f{t2.z, t2.w};
        w1p[2 * j]     = v2f{t1.x, t1.y};
        w1p[2 * j + 1] = v2f{t1.z, t1.w};
    }
    const float h2i = (h == 0) ? h2[y] : 0.0f;    // bias folded into acc init
    const float h1i = (oct == 0) ? h1[z] : 0.0f;
    const float Ar  = A[z];
    const bool  zdx = (z < DX);    // wave-uniform (waves 0-3)

    const float* Xb = X   + (size_t)b * TT * DX;
    float*       op = out + (size_t)b * TT * DX + z;
    const float* xq = Xb + DX + z;                 // X[t+1][z] stream
    const float NANF = __int_as_float(0x7fc00000);

    // ---- zf_0 = x0 (non-NaN) on first DX dims, else 0 (oct-replicated) ----
    float zfreg = 0.0f;
    if (zdx) { float x0 = Xb[z]; zfreg = (x0 == x0) ? x0 : 0.0f; }
    if (oct == 0) zf_s[z] = zfreg;
    __syncthreads();

    const int hidx = wv * HP + (y & 31);   // m1 write slot (h==0 lanes)

    for (int t = 0; t < TT; ++t) {
        // prefetch next forcing value (consumed at the m2 tail)
        float xnext = NANF;
        if (zdx && (t + 1) < TT) xnext = xq[0];
        xq += DX;

        // ---- m1: hidden = relu(W2 @ zf + h2) ----
        float4 zl4[8];
        {
            const float4* zp = (const float4*)(zf_s + 32 * h);
#pragma unroll
            for (int j = 0; j < 8; ++j) zl4[j] = zp[j];
        }
        v2f accA = {h2i, 0.f}, accB = {0.f, 0.f};
#pragma unroll
        for (int j = 0; j < 8; ++j) {
            accA = pk_fma(w2p[2 * j],     v2f{zl4[j].x, zl4[j].y}, accA);
            accB = pk_fma(w2p[2 * j + 1], v2f{zl4[j].z, zl4[j].w}, accB);
        }
        float d1 = (accA[0] + accB[0]) + (accA[1] + accB[1]);
        d1 = dpp_add<0xB1>(d1);                     // join the two z-halves
        if (h == 0) hid_s[hidx] = fmaxf(d1, 0.0f);
        __syncthreads();

        // ---- m2 + fused update: z_new = A*zf + W1 @ hidden + h1 ----
        float4 hl4[8];
        {
            const float4* hp = (const float4*)(hid_s + HP * oct);
#pragma unroll
            for (int j = 0; j < 8; ++j) hl4[j] = hp[j];
        }
        v2f acA = {h1i, 0.f}, acB = {0.f, 0.f};
#pragma unroll
        for (int j = 0; j < 8; ++j) {
            acA = pk_fma(w1p[2 * j],     v2f{hl4[j].x, hl4[j].y}, acA);
            acB = pk_fma(w1p[2 * j + 1], v2f{hl4[j].z, hl4[j].w}, acB);
        }
        float d2 = (acA[0] + acB[0]) + (acA[1] + acB[1]);
        d2 = dpp_add<0xB1>(d2);
        d2 = dpp_add<0x4E>(d2);
        d2 = dpp_add<0x141>(d2);                    // full 8-oct sum, all lanes

        float zn = fmaf(Ar, zfreg, d2);
        if (zdx) {                                  // wave-uniform branch
            if (oct == 0) *op = zn;
            zfreg = (xnext == xnext) ? fmaf(ALPHA, xnext, 0.875f * zn) : zn;
        } else {
            zfreg = zn;
        }
        if (oct == 0) zf_s[z] = zfreg;
        op += DX;
        __syncthreads();
    }
}

extern "C" void kernel_launch(void* const* d_in, const int* in_sizes, int n_in,
                              void* d_out, int out_size, void* d_ws, size_t ws_size,
                              hipStream_t stream) {
    const float* X  = (const float*)d_in[0];
    const float* A  = (const float*)d_in[1];
    const float* W1 = (const float*)d_in[2];
    const float* W2 = (const float*)d_in[3];
    const float* h1 = (const float*)d_in[4];
    const float* h2 = (const float*)d_in[5];
    float* out = (float*)d_out;

    plrnn_scan<<<BB, 512, 0, stream>>>(X, A, W1, W2, h1, h2, out);
}